// Round 2
// baseline (237.810 us; speedup 1.0000x reference)
//
#include <hip/hip_runtime.h>

// GraphEmbedder: B=8, C=64, G=65536, 4 layers of y=lrelu(W@[x; x-x0]), then max over G.
// Identity: W@[x; x-x0] = Wa@x - Wb@x0, Wa = W[:,:64]+W[:,64:], Wb = W[:,64:].
// R9: launch-structure round. R8 (-all weight LDS) was only -2.6us -> ge_main is near its
// HBM floor (~21us for 134MB features); remaining cost is structural. So:
//  - ge_prep FUSED into ge_fused: each block stages each 32KB W layer into LDS once,
//    extracts its lane's MFMA fragments (4x ds_read_b128 per fragment) and runs the exact
//    fp32 bias chain with 256-thread partials. Overlapped with 32 early feature loads.
//  - atomics/maxenc/encoding dropped: per-block raw max -> private ws slot (no init needed
//    on poisoned ws), ge_final reduces 512 slots. Stream ordering = coherence.
//  - prefetch depth 2 (nxtA/nxtB, statically indexed), covers ~900cy HBM latency at
//    2 waves/SIMD.
// ws float layout:
//  [0, 32768)      blockmax slots [bid][o], bid in [0,512)
//  [32768, 33280)  nbias3 [b][o] (negated layer-3 bias, written by blocks with blk==0)

#define G_TOT 65536

typedef _Float16 hf2 __attribute__((ext_vector_type(2)));
typedef _Float16 hf4 __attribute__((ext_vector_type(4)));
typedef _Float16 hf8 __attribute__((ext_vector_type(8)));
typedef float float4_ __attribute__((ext_vector_type(4)));

static __device__ __forceinline__ hf2 pkh(float x, float y) {
    return __builtin_bit_cast(hf2, __builtin_amdgcn_cvt_pkrtz(x, y));
}

__global__ __launch_bounds__(256, 2) void ge_fused(
    const float* __restrict__ feat,
    const float* __restrict__ W0, const float* __restrict__ W1,
    const float* __restrict__ W2, const float* __restrict__ W3,
    float* __restrict__ ws)
{
    __shared__ __align__(16) float stg[64][132];   // staged W layer, padded (132%4==0 -> b128 ok)
    __shared__ float xch[2][64];
    __shared__ float part1[64][4];
    __shared__ float part2[64][4];
    __shared__ __align__(16) float lbias[192];     // negated bias, layers 0..2
    __shared__ float nb3[64];                      // negated layer-3 bias
    __shared__ float blockmax[4][64];

    const int tid = threadIdx.x;
    const int b = blockIdx.x >> 6;                 // 64 blocks/batch, 1024 cols each
    const int w = tid >> 6, lane = tid & 63, q = lane >> 4, n = lane & 15;
    const int g0 = ((blockIdx.x & 63) << 10) + (w << 8);   // 256 cols per wave
    const float* Xrow = feat + (size_t)b * 64 * G_TOT + (size_t)(q << 2) * G_TOT;

    // ---- early feature prefetch: tiles 0 and 1 stay in flight through the prep phase ----
    float nxtA[16], nxtB[16];
    {
        int ga = g0 + n;
#pragma unroll
        for (int kf = 0; kf < 4; ++kf)
#pragma unroll
            for (int r = 0; r < 4; ++r) {
                size_t off = (size_t)((kf << 4) + r) * G_TOT;
                nxtA[kf * 4 + r] = Xrow[off + ga];
                nxtB[kf * 4 + r] = Xrow[off + ga + 16];
            }
    }
    if (tid < 64) xch[0][tid] = feat[(size_t)(b * 64 + tid) * G_TOT];

    // ---- in-block prep: weight fragments (f16) + exact fp32 bias chain ----
    hf8 wfr[4][4][2];
#pragma unroll
    for (int l = 0; l < 4; ++l) {                  // unrolled: wfr[l] statically indexed
        const float* Wl = (l == 0) ? W0 : (l == 1) ? W1 : (l == 2) ? W2 : W3;
#pragma unroll
        for (int k = 0; k < 8; ++k) {              // stage 64x128 f32 via float4
            int i = tid + (k << 8);
            *(float4_*)&stg[i >> 5][(i & 31) << 2] =
                *(const float4_*)&Wl[(i >> 5) * 128 + ((i & 31) << 2)];
        }
        __syncthreads();
        // per-lane MFMA fragments: Wa[o][c] = W[o][c] + W[o][64+c]
        // elem e of frag (l,mt,pr): o = 16*mt + n, c = 32*pr + 16*(e>>2) + 4*q + (e&3)
#pragma unroll
        for (int mt = 0; mt < 4; ++mt)
#pragma unroll
            for (int pr = 0; pr < 2; ++pr) {
                int o = (mt << 4) + n, base = (pr << 5) + (q << 2);
                float4_ a0 = *(const float4_*)&stg[o][base];
                float4_ a1 = *(const float4_*)&stg[o][base + 16];
                float4_ c0 = *(const float4_*)&stg[o][base + 64];
                float4_ c1 = *(const float4_*)&stg[o][base + 80];
                a0 += c0; a1 += c1;
                union { hf2 h2[4]; hf8 h8; } u;
                u.h2[0] = pkh(a0[0], a0[1]); u.h2[1] = pkh(a0[2], a0[3]);
                u.h2[2] = pkh(a1[0], a1[1]); u.h2[3] = pkh(a1[2], a1[3]);
                wfr[l][mt][pr] = u.h8;
            }
        // bias-chain partials: s1 = W[:,:64]@x0 (chain), s2 = W[:,64:]@x0 (bias)
        {
            int o = tid & 63, cq = tid >> 6;
            float s1 = 0.f, s2 = 0.f;
            const float* xs = xch[l & 1];
#pragma unroll
            for (int c16 = 0; c16 < 16; ++c16) {
                int c = (cq << 4) + c16;
                float xv = xs[c];
                s1 += stg[o][c] * xv;
                s2 += stg[o][64 + c] * xv;
            }
            part1[o][cq] = s1; part2[o][cq] = s2;
        }
        __syncthreads();
        if (tid < 64) {
            float S1 = part1[tid][0] + part1[tid][1] + part1[tid][2] + part1[tid][3];
            float S2 = part2[tid][0] + part2[tid][1] + part2[tid][2] + part2[tid][3];
            if (l < 3) {
                lbias[(l << 6) + tid] = -S2;
                xch[(l & 1) ^ 1][tid] = fmaxf(S1, 0.1f * S1);
            } else {
                nb3[tid] = -S2;
            }
        }
        // next iteration's post-staging sync (or the sync below) orders these writes
    }
    __syncthreads();

    // ---- main loop: 16 tiles of 16 cols, depth-2 register prefetch ----
    float rmax[4][4];
#pragma unroll
    for (int mt = 0; mt < 4; ++mt)
#pragma unroll
        for (int j = 0; j < 4; ++j) rmax[mt][j] = -__builtin_inff();

    const hf4 k01 = { (_Float16)0.1f, (_Float16)0.1f, (_Float16)0.1f, (_Float16)0.1f };

    auto compute = [&](hf4* bf) {
#pragma unroll
        for (int l = 0; l < 4; ++l) {
            float4_ acc[4];
#pragma unroll
            for (int mt = 0; mt < 4; ++mt) {
                if (l < 3) acc[mt] = *(const float4_*)&lbias[(l << 6) + (mt << 4) + (q << 2)];
                else       acc[mt] = float4_{0.f, 0.f, 0.f, 0.f};   // layer-3 bias deferred
            }
#pragma unroll
            for (int mt = 0; mt < 4; ++mt)
#pragma unroll
                for (int pr = 0; pr < 2; ++pr) {
                    union { hf8 h8; hf4 h4[2]; } ua;
                    ua.h8 = wfr[l][mt][pr];
                    acc[mt] = __builtin_amdgcn_mfma_f32_16x16x16f16(ua.h4[0], bf[(pr << 1) + 0], acc[mt], 0, 0, 0);
                    acc[mt] = __builtin_amdgcn_mfma_f32_16x16x16f16(ua.h4[1], bf[(pr << 1) + 1], acc[mt], 0, 0, 0);
                }
            if (l < 3) {
#pragma unroll
                for (int mt = 0; mt < 4; ++mt) {   // packed-f16 leaky-relu
                    union { hf2 h2[2]; hf4 h4; } u;
                    u.h2[0] = pkh(acc[mt][0], acc[mt][1]);
                    u.h2[1] = pkh(acc[mt][2], acc[mt][3]);
                    hf4 h = u.h4;
                    h = __builtin_elementwise_max(h, h * k01);
                    bf[mt] = h;
                }
            } else {
                // raw max only; bias + lrelu applied once in ge_final (commute with max)
#pragma unroll
                for (int mt = 0; mt < 4; ++mt)
#pragma unroll
                    for (int j = 0; j < 4; ++j)
                        rmax[mt][j] = fmaxf(rmax[mt][j], acc[mt][j]);
            }
        }
    };

#pragma unroll 1
    for (int nt = 0; nt < 16; nt += 2) {
        hf4 bf[4];
#pragma unroll
        for (int kf = 0; kf < 4; ++kf) {
            union { hf2 h2[2]; hf4 h4; } u;
            u.h2[0] = pkh(nxtA[kf * 4 + 0], nxtA[kf * 4 + 1]);
            u.h2[1] = pkh(nxtA[kf * 4 + 2], nxtA[kf * 4 + 3]);
            bf[kf] = u.h4;
        }
        if (nt < 14) {
            int gcol = g0 + ((nt + 2) << 4) + n;
#pragma unroll
            for (int kf = 0; kf < 4; ++kf)
#pragma unroll
                for (int r = 0; r < 4; ++r)
                    nxtA[kf * 4 + r] = Xrow[(size_t)((kf << 4) + r) * G_TOT + gcol];
        }
        compute(bf);

#pragma unroll
        for (int kf = 0; kf < 4; ++kf) {
            union { hf2 h2[2]; hf4 h4; } u;
            u.h2[0] = pkh(nxtB[kf * 4 + 0], nxtB[kf * 4 + 1]);
            u.h2[1] = pkh(nxtB[kf * 4 + 2], nxtB[kf * 4 + 3]);
            bf[kf] = u.h4;
        }
        if (nt < 14) {
            int gcol = g0 + ((nt + 3) << 4) + n;
#pragma unroll
            for (int kf = 0; kf < 4; ++kf)
#pragma unroll
                for (int r = 0; r < 4; ++r)
                    nxtB[kf * 4 + r] = Xrow[(size_t)((kf << 4) + r) * G_TOT + gcol];
        }
        compute(bf);
    }

    // ---- reduce over 16 column-lanes, then block, then write raw-max slot ----
#pragma unroll
    for (int mt = 0; mt < 4; ++mt)
#pragma unroll
        for (int j = 0; j < 4; ++j) {
            float v = rmax[mt][j];
            v = fmaxf(v, __shfl_xor(v, 1, 64));
            v = fmaxf(v, __shfl_xor(v, 2, 64));
            v = fmaxf(v, __shfl_xor(v, 4, 64));
            v = fmaxf(v, __shfl_xor(v, 8, 64));
            rmax[mt][j] = v;
        }
    if (n == 0) {
#pragma unroll
        for (int mt = 0; mt < 4; ++mt)
#pragma unroll
            for (int j = 0; j < 4; ++j)
                blockmax[w][(mt << 4) + (q << 2) + j] = rmax[mt][j];
    }
    __syncthreads();
    if (tid < 64) {
        float v = fmaxf(fmaxf(blockmax[0][tid], blockmax[1][tid]),
                        fmaxf(blockmax[2][tid], blockmax[3][tid]));
        ws[(size_t)blockIdx.x * 64 + tid] = v;                 // raw max, private slot
        if ((blockIdx.x & 63) == 0) ws[32768 + (b << 6) + tid] = nb3[tid];
    }
}

__global__ void ge_final(const float* __restrict__ ws, float* __restrict__ out)
{
    int i = threadIdx.x;
    if (i < 512) {
        int b = i >> 6, o = i & 63;
        const float* base = ws + (size_t)(b << 6) * 64 + o;
        float m = -__builtin_inff();
#pragma unroll
        for (int blk = 0; blk < 64; ++blk)
            m = fmaxf(m, base[blk * 64]);
        // deferred layer-3 bias + leaky-relu (both commute with max over G)
        float v = m + ws[32768 + i];
        out[i] = fmaxf(v, 0.1f * v);
    }
}

extern "C" void kernel_launch(void* const* d_in, const int* in_sizes, int n_in,
                              void* d_out, int out_size, void* d_ws, size_t ws_size,
                              hipStream_t stream) {
    const float* feat = (const float*)d_in[0];
    const float* W0 = (const float*)d_in[1];
    const float* W1 = (const float*)d_in[2];
    const float* W2 = (const float*)d_in[3];
    const float* W3 = (const float*)d_in[4];
    float* ws = (float*)d_ws;

    ge_fused<<<512, 256, 0, stream>>>(feat, W0, W1, W2, W3, ws);
    ge_final<<<1, 512, 0, stream>>>(ws, (float*)d_out);
}

// Round 3
// 222.373 us; speedup vs baseline: 1.0694x; 1.0694x over previous
//
#include <hip/hip_runtime.h>

// GraphEmbedder: B=8, C=64, G=65536, 4 layers of y=lrelu(W@[x; x-x0]), then max over G.
// Identity: W@[x; x-x0] = Wa@x - Wb@x0, Wa = W[:,:64]+W[:,64:], Wb = W[:,64:].
// R10 = R8 skeleton (separate ge_prep; weights resident in 128 VGPRs from prep-emitted
// f16 fragment image; layer-3 bias deferred to ge_final; atomicMax epilogue) with ONE
// change: the feature stream now loads float2 per lane (lane n owns cols 2n,2n+1 of a
// 32-col group) -> per instruction 4x128B dense cache-line segments instead of 4x64B,
// half the load instructions, 2x in-flight bytes. Columns land permuted across MFMA
// tiles, which is harmless: we only max over G.
// R9 lesson: no pointer-taking lambdas (scratch spill, WRITE_SIZE 23MB); compute is a
// macro, every array index static, live regs ~229 < 256.

#define G_TOT 65536

typedef _Float16 hf2 __attribute__((ext_vector_type(2)));
typedef _Float16 hf4 __attribute__((ext_vector_type(4)));
typedef _Float16 hf8 __attribute__((ext_vector_type(8)));
typedef float float2_ __attribute__((ext_vector_type(2)));
typedef float float4_ __attribute__((ext_vector_type(4)));

static __device__ __forceinline__ hf2 pkh(float x, float y) {
    return __builtin_bit_cast(hf2, __builtin_amdgcn_cvt_pkrtz(x, y));
}

// ws layout (floats):
//   [0, 8192)       wf16: 16384 f16 weight fragments, frag-major
//                   elem (f*512 + lane*8 + e) = f16(Wa[l][16*mt+(lane&15)][32*pr+16*(e>>2)+4*(lane>>4)+(e&3)])
//                   with f = ((l*4+mt)*2+pr)
//   [16384, 18432)  nbias[b][l][o] fp32 (NEGATED bias)
//   [18432, 18944)  maxenc (uint32 ordered-float), zeroed by prep

__global__ __launch_bounds__(256) void ge_prep(
    const float* __restrict__ feat,
    const float* __restrict__ W0, const float* __restrict__ W1,
    const float* __restrict__ W2, const float* __restrict__ W3,
    float* __restrict__ ws)
{
    const int tid = threadIdx.x;
    const int blk = blockIdx.x;
    __shared__ float lw[64][129];
    __shared__ float x0[2][64];

    if (blk == 8) {
        // maxenc init + f16 fragment image of Wa = W[:,:64] + W[:,64:]
        unsigned* maxenc = (unsigned*)(ws + 18432);
        maxenc[tid] = 0u; maxenc[tid + 256] = 0u;
        _Float16* wf = (_Float16*)ws;
        for (int ci = tid; ci < 8192; ci += 256) {       // ci indexes hf2 chunks
            int f = ci >> 8, ln = (ci >> 2) & 63, h2 = ci & 3;
            int l = f >> 3, mt = (f >> 1) & 3, pr = f & 1;
            int o = (mt << 4) + (ln & 15);
            int c = (pr << 5) + ((h2 >> 1) << 4) + ((ln >> 4) << 2) + ((h2 & 1) << 1);
            const float* Wl = (l == 0) ? W0 : (l == 1) ? W1 : (l == 2) ? W2 : W3;
            float a0 = Wl[o * 128 + c]     + Wl[o * 128 + 64 + c];
            float a1 = Wl[o * 128 + c + 1] + Wl[o * 128 + 64 + c + 1];
            *(hf2*)&wf[ci << 1] = pkh(a0, a1);
        }
        return;
    }

    // blocks 0..7: exact fp32 bias chain for batch b = blk
    const int b = blk;
    if (tid < 64) x0[0][tid] = feat[(size_t)(b * 64 + tid) * G_TOT];
    float* nbias = ws + 16384;
    for (int l = 0; l < 4; ++l) {
        const float* Wl = (l == 0) ? W0 : (l == 1) ? W1 : (l == 2) ? W2 : W3;
        for (int i = tid; i < 64 * 128; i += 256) lw[i >> 7][i & 127] = Wl[i];
        __syncthreads();
        if (tid < 64) {
            const int o = tid;
            const float* src = x0[l & 1];
            float s1 = 0.f, s2 = 0.f;
            for (int c = 0; c < 64; ++c) {
                float xv = src[c];
                s1 += lw[o][c] * xv;
                s2 += lw[o][64 + c] * xv;
            }
            nbias[b * 256 + l * 64 + o] = -s2;          // negated, [b][l][o]
            x0[(l & 1) ^ 1][o] = fmaxf(s1, 0.1f * s1);
        }
        __syncthreads();
    }
}

// compute one 16-col tile: 4-layer MFMA chain on fragment array BF (hf4[4]),
// accumulating raw layer-3 max into rmax. All indices static (full unroll).
#define COMPUTE_TILE(BF)                                                              \
    _Pragma("unroll")                                                                 \
    for (int l = 0; l < 4; ++l) {                                                     \
        float4_ acc[4];                                                               \
        _Pragma("unroll")                                                             \
        for (int mt = 0; mt < 4; ++mt) {                                              \
            if (l < 3) acc[mt] = *(const float4_*)&lbias[(l << 6) + (mt << 4) + (q << 2)]; \
            else       acc[mt] = float4_{0.f, 0.f, 0.f, 0.f};                         \
        }                                                                             \
        _Pragma("unroll")                                                             \
        for (int mt = 0; mt < 4; ++mt) {                                              \
            _Pragma("unroll")                                                         \
            for (int pr = 0; pr < 2; ++pr) {                                          \
                union { hf8 h8; hf4 h4[2]; } ua;                                      \
                ua.h8 = wfr[l][mt][pr];                                               \
                acc[mt] = __builtin_amdgcn_mfma_f32_16x16x16f16(ua.h4[0], BF[(pr << 1) + 0], acc[mt], 0, 0, 0); \
                acc[mt] = __builtin_amdgcn_mfma_f32_16x16x16f16(ua.h4[1], BF[(pr << 1) + 1], acc[mt], 0, 0, 0); \
            }                                                                         \
        }                                                                             \
        if (l < 3) {                                                                  \
            _Pragma("unroll")                                                         \
            for (int mt = 0; mt < 4; ++mt) {                                          \
                union { hf2 h2[2]; hf4 h4; } u;                                       \
                u.h2[0] = pkh(acc[mt][0], acc[mt][1]);                                \
                u.h2[1] = pkh(acc[mt][2], acc[mt][3]);                                \
                hf4 h = u.h4;                                                         \
                h = __builtin_elementwise_max(h, h * k01);                            \
                BF[mt] = h;                                                           \
            }                                                                         \
        } else {                                                                      \
            _Pragma("unroll")                                                         \
            for (int mt = 0; mt < 4; ++mt)                                            \
                _Pragma("unroll")                                                     \
                for (int j = 0; j < 4; ++j)                                           \
                    rmax[mt][j] = fmaxf(rmax[mt][j], acc[mt][j]);                     \
        }                                                                             \
    }

__global__ __launch_bounds__(256, 2) void ge_main(
    const float* __restrict__ feat,
    const float* __restrict__ ws_wf,
    const float* __restrict__ nbias,
    unsigned* __restrict__ maxenc)
{
    __shared__ float lbias[256];
    __shared__ float blockmax[4][64];
    const int tid = threadIdx.x;
    const int b = blockIdx.x >> 6;      // 64 blocks per batch, 1024 cols each
    const int w = tid >> 6, lane = tid & 63, q = lane >> 4, n = lane & 15;
    const int g0 = ((blockIdx.x & 63) << 10) + (w << 8);   // 256 cols per wave

    // per-lane stream base: row block 4q, cols g0 + 2n (+1)
    const float* Xbase = feat + (size_t)b * 64 * G_TOT + (size_t)(q << 2) * G_TOT
                       + (size_t)g0 + (size_t)(n << 1);

    // ---- issue group-0 feature loads first (HBM latency hides under wfr/L2 reads) ----
    float2_ buf[16];
#pragma unroll
    for (int kf = 0; kf < 4; ++kf)
#pragma unroll
        for (int r = 0; r < 4; ++r)
            buf[kf * 4 + r] = *(const float2_*)&Xbase[(size_t)((kf << 4) + r) * G_TOT];

    // all 4 layers' weight fragments -> 128 VGPRs, read once (L2-broadcast 16 KB)
    hf8 wfr[4][4][2];
    {
        const hf8* wp = (const hf8*)ws_wf;
#pragma unroll
        for (int l = 0; l < 4; ++l)
#pragma unroll
            for (int mt = 0; mt < 4; ++mt)
#pragma unroll
                for (int pr = 0; pr < 2; ++pr)
                    wfr[l][mt][pr] = wp[((((((l << 2) + mt) << 1) + pr)) << 6) + lane];
    }

    lbias[tid] = nbias[(b << 8) + tid];
    __syncthreads();

    float rmax[4][4];
#pragma unroll
    for (int mt = 0; mt < 4; ++mt)
#pragma unroll
        for (int j = 0; j < 4; ++j) rmax[mt][j] = -__builtin_inff();

    const hf4 k01 = { (_Float16)0.1f, (_Float16)0.1f, (_Float16)0.1f, (_Float16)0.1f };

    // ---- main loop: 8 groups of 32 cols; each group = 2 MFMA tiles (even/odd cols) ----
#pragma unroll 1
    for (int grp = 0; grp < 8; ++grp) {
        // unpack both tiles from buf (waits on this group's loads), freeing buf
        hf4 bfA[4], bfB[4];
#pragma unroll
        for (int kf = 0; kf < 4; ++kf) {
            union { hf2 h2[2]; hf4 h4; } ua, ub;
            ua.h2[0] = pkh(buf[kf * 4 + 0][0], buf[kf * 4 + 1][0]);
            ua.h2[1] = pkh(buf[kf * 4 + 2][0], buf[kf * 4 + 3][0]);
            ub.h2[0] = pkh(buf[kf * 4 + 0][1], buf[kf * 4 + 1][1]);
            ub.h2[1] = pkh(buf[kf * 4 + 2][1], buf[kf * 4 + 3][1]);
            bfA[kf] = ua.h4;
            bfB[kf] = ub.h4;
        }
        // issue next group's loads; they fly under ~2 tile-computes
        if (grp < 7) {
            const float* Xp = Xbase + ((grp + 1) << 5);
#pragma unroll
            for (int kf = 0; kf < 4; ++kf)
#pragma unroll
                for (int r = 0; r < 4; ++r)
                    buf[kf * 4 + r] = *(const float2_*)&Xp[(size_t)((kf << 4) + r) * G_TOT];
        }
        COMPUTE_TILE(bfA)
        COMPUTE_TILE(bfB)
    }

    // ---- reduce raw max over 16 column-lanes ----
#pragma unroll
    for (int mt = 0; mt < 4; ++mt)
#pragma unroll
        for (int j = 0; j < 4; ++j) {
            float v = rmax[mt][j];
            v = fmaxf(v, __shfl_xor(v, 1, 64));
            v = fmaxf(v, __shfl_xor(v, 2, 64));
            v = fmaxf(v, __shfl_xor(v, 4, 64));
            v = fmaxf(v, __shfl_xor(v, 8, 64));
            rmax[mt][j] = v;
        }
    if (n == 0) {
#pragma unroll
        for (int mt = 0; mt < 4; ++mt)
#pragma unroll
            for (int j = 0; j < 4; ++j)
                blockmax[w][(mt << 4) + (q << 2) + j] = rmax[mt][j];
    }
    __syncthreads();
    if (tid < 64) {
        float v = fmaxf(fmaxf(blockmax[0][tid], blockmax[1][tid]),
                        fmaxf(blockmax[2][tid], blockmax[3][tid]));
        unsigned s = __float_as_uint(v);
        unsigned enc = (s & 0x80000000u) ? ~s : (s | 0x80000000u);
        atomicMax(&maxenc[b * 64 + tid], enc);
    }
}

__global__ void ge_final(const unsigned* __restrict__ maxenc,
                         const float* __restrict__ nbias,
                         float* __restrict__ out)
{
    int i = threadIdx.x;
    if (i < 512) {
        unsigned u = maxenc[i];
        unsigned s = (u & 0x80000000u) ? (u ^ 0x80000000u) : ~u;
        // deferred layer-3 bias + leaky-relu (both commute with max over G)
        float v = __uint_as_float(s) + nbias[((i >> 6) << 8) + 192 + (i & 63)];
        out[i] = fmaxf(v, 0.1f * v);
    }
}

extern "C" void kernel_launch(void* const* d_in, const int* in_sizes, int n_in,
                              void* d_out, int out_size, void* d_ws, size_t ws_size,
                              hipStream_t stream) {
    const float* feat = (const float*)d_in[0];
    const float* W0 = (const float*)d_in[1];
    const float* W1 = (const float*)d_in[2];
    const float* W2 = (const float*)d_in[3];
    const float* W3 = (const float*)d_in[4];
    float* ws = (float*)d_ws;
    unsigned* maxenc = (unsigned*)(ws + 18432);

    ge_prep<<<9, 256, 0, stream>>>(feat, W0, W1, W2, W3, ws);
    ge_main<<<512, 256, 0, stream>>>(feat, ws, ws + 16384, maxenc);
    ge_final<<<1, 512, 0, stream>>>(maxenc, ws + 16384, (float*)d_out);
}